// Round 1
// baseline (5421.386 us; speedup 1.0000x reference)
//
#include <hip/hip_runtime.h>
#include <math.h>

#define S_LEN 4096
#define D_MODEL 2048
#define N_HEADS 16
#define N_KV 4
#define HEAD_DIM 128
#define KV_D (N_KV * HEAD_DIM) // 512

// ---------------------------------------------------------------------------
// fp32 tiled GEMM: C = A(MxK) @ B(KxN), all row-major.
// 128x128 block tile, BK=8, 256 threads, 8x8 microtile (split 4+4 with +64
// offset so LDS read addresses stride by 4 floats -> <=2-way conflicts, free).
// ---------------------------------------------------------------------------
__global__ __launch_bounds__(256) void sgemm_kernel(
    const float* __restrict__ A, const float* __restrict__ B,
    float* __restrict__ C, int M, int N, int K) {
  __shared__ float As[8][132];  // transposed: As[k][m]
  __shared__ float Bs[8][132];
  const int t = threadIdx.x;
  const int row0 = blockIdx.y * 128;
  const int col0 = blockIdx.x * 128;
  const int a_row = t >> 1, a_col = (t & 1) * 4;   // A tile: 128 rows x 8 k
  const int b_row = t >> 5, b_col = (t & 31) * 4;  // B tile: 8 k x 128 cols
  const int ty = t >> 4, tx = t & 15;

  float acc[8][8];
#pragma unroll
  for (int i = 0; i < 8; i++)
#pragma unroll
    for (int j = 0; j < 8; j++) acc[i][j] = 0.f;

  const float* Aptr = A + (size_t)(row0 + a_row) * K + a_col;
  const float* Bptr = B + (size_t)b_row * N + col0 + b_col;

  for (int kk = 0; kk < K; kk += 8) {
    float4 av = *(const float4*)(Aptr + kk);
    float4 bv = *(const float4*)(Bptr + (size_t)kk * N);
    __syncthreads();  // previous iteration's compute done before overwrite
    As[a_col + 0][a_row] = av.x;
    As[a_col + 1][a_row] = av.y;
    As[a_col + 2][a_row] = av.z;
    As[a_col + 3][a_row] = av.w;
    *(float4*)&Bs[b_row][b_col] = bv;
    __syncthreads();
#pragma unroll
    for (int k = 0; k < 8; k++) {
      float4 a0 = *(float4*)&As[k][ty * 4];
      float4 a1 = *(float4*)&As[k][64 + ty * 4];
      float4 b0 = *(float4*)&Bs[k][tx * 4];
      float4 b1 = *(float4*)&Bs[k][64 + tx * 4];
      float ar[8] = {a0.x, a0.y, a0.z, a0.w, a1.x, a1.y, a1.z, a1.w};
      float br[8] = {b0.x, b0.y, b0.z, b0.w, b1.x, b1.y, b1.z, b1.w};
#pragma unroll
      for (int i = 0; i < 8; i++)
#pragma unroll
        for (int j = 0; j < 8; j++) acc[i][j] = fmaf(ar[i], br[j], acc[i][j]);
    }
  }

#pragma unroll
  for (int i = 0; i < 8; i++) {
    int r = row0 + ((i < 4) ? (ty * 4 + i) : (64 + ty * 4 + (i - 4)));
    float4 c0 = make_float4(acc[i][0], acc[i][1], acc[i][2], acc[i][3]);
    float4 c1 = make_float4(acc[i][4], acc[i][5], acc[i][6], acc[i][7]);
    *(float4*)&C[(size_t)r * N + col0 + tx * 4] = c0;
    *(float4*)&C[(size_t)r * N + col0 + 64 + tx * 4] = c1;
  }
}

// ---------------------------------------------------------------------------
// RoPE in place on Q (S x H*HD) and K (S x KV*HD). One thread per (s,head,d)
// pair, rotating (d, d+64) within the head.
// ---------------------------------------------------------------------------
__global__ __launch_bounds__(256) void rope_kernel(float* __restrict__ Q,
                                                   float* __restrict__ Kb) {
  int id = blockIdx.x * 256 + threadIdx.x;  // S_LEN * 20 * 64 total
  int d = id & 63;
  int rem = id >> 6;          // s*20 + head
  int head = rem % 20;
  int s = rem / 20;
  float* p;
  if (head < N_HEADS)
    p = Q + (size_t)s * D_MODEL + head * HEAD_DIM;
  else
    p = Kb + (size_t)s * KV_D + (head - N_HEADS) * HEAD_DIM;
  // inv_freq = 10000^(-d/64) = 2^(-d * log2(10000)/64)
  float inv = exp2f(-(float)d * (13.287712379549449f / 64.0f));
  float ang = (float)s * inv;
  float sn, c;
  sincosf(ang, &sn, &c);
  float xr = p[d], xi = p[d + 64];
  p[d] = xr * c - xi * sn;
  p[d + 64] = xr * sn + xi * c;
}

// ---------------------------------------------------------------------------
// Flash attention, fp32. Block = 256 threads = one (head, 32-query tile).
// K/V staged in LDS (32 rows), online softmax, O accumulator in registers.
// GQA: head h uses kv head h/4.
// ---------------------------------------------------------------------------
__global__ __launch_bounds__(256) void attn_kernel(
    const float* __restrict__ Q, const float* __restrict__ Kb,
    const float* __restrict__ Vb, float* __restrict__ O) {
  __shared__ float Qs[32][132];
  __shared__ float Ks[32][132];
  __shared__ float Vs[32][132];
  __shared__ float Ss[32][33];
  __shared__ float m_s[32], l_s[32], alpha_s[32];

  const int t = threadIdx.x;
  const int qt = blockIdx.x;    // query tile 0..127
  const int h = blockIdx.y;     // head 0..15
  const int kv = h >> 2;        // GQA group

  // load Q tile (32 x 128)
  const float* qbase = Q + (size_t)(qt * 32) * D_MODEL + h * HEAD_DIM;
#pragma unroll
  for (int i = 0; i < 4; i++) {
    int f = t + 256 * i;              // float4 index 0..1023
    int r = f >> 5, c4 = (f & 31) * 4;
    *(float4*)&Qs[r][c4] = *(const float4*)(qbase + (size_t)r * D_MODEL + c4);
  }
  if (t < 32) { m_s[t] = -1e30f; l_s[t] = 0.f; }

  float4 o[4];
#pragma unroll
  for (int j = 0; j < 4; j++) o[j] = make_float4(0.f, 0.f, 0.f, 0.f);

  const int tq = t >> 4, tk = t & 15;  // scores: q in {2tq,2tq+1}, k in {tk,tk+16}
  const int oq = t >> 3, dg = t & 7;   // O phase: q = oq, dims 4*dg + 32*j
  const float sc = 0.08838834764831845f;  // 1/sqrt(128)

  __syncthreads();

  for (int kt = 0; kt < S_LEN / 32; kt++) {
    const float* kbase = Kb + (size_t)(kt * 32) * KV_D + kv * HEAD_DIM;
    const float* vbase = Vb + (size_t)(kt * 32) * KV_D + kv * HEAD_DIM;
#pragma unroll
    for (int i = 0; i < 4; i++) {
      int f = t + 256 * i;
      int r = f >> 5, c4 = (f & 31) * 4;
      *(float4*)&Ks[r][c4] = *(const float4*)(kbase + (size_t)r * KV_D + c4);
      *(float4*)&Vs[r][c4] = *(const float4*)(vbase + (size_t)r * KV_D + c4);
    }
    __syncthreads();

    // scores: each thread 2 q x 2 k
    float s00 = 0.f, s01 = 0.f, s10 = 0.f, s11 = 0.f;
#pragma unroll 8
    for (int j = 0; j < 128; j += 4) {
      float4 qa = *(float4*)&Qs[2 * tq][j];
      float4 qb = *(float4*)&Qs[2 * tq + 1][j];
      float4 ka = *(float4*)&Ks[tk][j];
      float4 kb2 = *(float4*)&Ks[tk + 16][j];
      s00 += qa.x * ka.x + qa.y * ka.y + qa.z * ka.z + qa.w * ka.w;
      s01 += qa.x * kb2.x + qa.y * kb2.y + qa.z * kb2.z + qa.w * kb2.w;
      s10 += qb.x * ka.x + qb.y * ka.y + qb.z * ka.z + qb.w * ka.w;
      s11 += qb.x * kb2.x + qb.y * kb2.y + qb.z * kb2.z + qb.w * kb2.w;
    }
    Ss[2 * tq][tk] = s00 * sc;
    Ss[2 * tq][tk + 16] = s01 * sc;
    Ss[2 * tq + 1][tk] = s10 * sc;
    Ss[2 * tq + 1][tk + 16] = s11 * sc;
    __syncthreads();

    // online softmax per query row
    if (t < 32) {
      float m_old = m_s[t], mn = m_old;
#pragma unroll
      for (int k = 0; k < 32; k++) mn = fmaxf(mn, Ss[t][k]);
      float al = expf(m_old - mn);
      float sum = 0.f;
#pragma unroll
      for (int k = 0; k < 32; k++) {
        float p = expf(Ss[t][k] - mn);
        Ss[t][k] = p;
        sum += p;
      }
      m_s[t] = mn;
      l_s[t] = l_s[t] * al + sum;
      alpha_s[t] = al;
    }
    __syncthreads();

    // O update: o[q][d] = o*alpha + sum_k p[q][k] * V[k][d]
    float al = alpha_s[oq];
#pragma unroll
    for (int j = 0; j < 4; j++) {
      o[j].x *= al; o[j].y *= al; o[j].z *= al; o[j].w *= al;
    }
    for (int k = 0; k < 32; k++) {
      float p = Ss[oq][k];
#pragma unroll
      for (int j = 0; j < 4; j++) {
        float4 v = *(float4*)&Vs[k][4 * dg + 32 * j];
        o[j].x += p * v.x; o[j].y += p * v.y;
        o[j].z += p * v.z; o[j].w += p * v.w;
      }
    }
    __syncthreads();  // before next tile overwrites Ks/Vs/Ss
  }

  float linv = 1.0f / l_s[oq];
  float* obase = O + (size_t)(qt * 32 + oq) * D_MODEL + h * HEAD_DIM;
#pragma unroll
  for (int j = 0; j < 4; j++) {
    float4 v = o[j];
    v.x *= linv; v.y *= linv; v.z *= linv; v.w *= linv;
    *(float4*)(obase + 4 * dg + 32 * j) = v;
  }
}

// ---------------------------------------------------------------------------
extern "C" void kernel_launch(void* const* d_in, const int* in_sizes, int n_in,
                              void* d_out, int out_size, void* d_ws,
                              size_t ws_size, hipStream_t stream) {
  const float* X = (const float*)d_in[0];   // 4096 x 2048
  const float* Wq = (const float*)d_in[1];  // 2048 x 2048
  const float* Wk = (const float*)d_in[2];  // 2048 x 512
  const float* Wv = (const float*)d_in[3];  // 2048 x 512
  const float* Wo = (const float*)d_in[4];  // 2048 x 2048
  float* out = (float*)d_out;               // 4096 x 2048

  char* ws = (char*)d_ws;
  float* Qw = (float*)ws;                           // 4096*2048 f32 = 32 MiB
  float* Kw = (float*)(ws + (size_t)33554432);      // 4096*512  f32 =  8 MiB
  float* Vw = (float*)(ws + (size_t)41943040);      // 4096*512  f32 =  8 MiB
  float* Ow = (float*)(ws + (size_t)50331648);      // 4096*2048 f32 = 32 MiB

  dim3 blk(256);
  // QKV projections
  sgemm_kernel<<<dim3(D_MODEL / 128, S_LEN / 128), blk, 0, stream>>>(
      X, Wq, Qw, S_LEN, D_MODEL, D_MODEL);
  sgemm_kernel<<<dim3(KV_D / 128, S_LEN / 128), blk, 0, stream>>>(
      X, Wk, Kw, S_LEN, KV_D, D_MODEL);
  sgemm_kernel<<<dim3(KV_D / 128, S_LEN / 128), blk, 0, stream>>>(
      X, Wv, Vw, S_LEN, KV_D, D_MODEL);
  // RoPE on Q and K
  rope_kernel<<<(S_LEN * (N_HEADS + N_KV) * 64) / 256, blk, 0, stream>>>(Qw, Kw);
  // attention
  attn_kernel<<<dim3(S_LEN / 32, N_HEADS), blk, 0, stream>>>(Qw, Kw, Vw, Ow);
  // output projection
  sgemm_kernel<<<dim3(D_MODEL / 128, S_LEN / 128), blk, 0, stream>>>(
      Ow, Wo, out, S_LEN, D_MODEL, D_MODEL);
}

// Round 2
// 1830.733 us; speedup vs baseline: 2.9613x; 2.9613x over previous
//
#include <hip/hip_runtime.h>
#include <math.h>

#define S_LEN 4096
#define D_MODEL 2048
#define N_HEADS 16
#define N_KV 4
#define HEAD_DIM 128
#define KV_D (N_KV * HEAD_DIM) // 512

typedef short bf16x8 __attribute__((ext_vector_type(8)));
typedef float f32x4 __attribute__((ext_vector_type(4)));

static __device__ __forceinline__ unsigned short f2b(float f) {
  unsigned int u = __float_as_uint(f);
  unsigned int r = (u + 0x7FFFu + ((u >> 16) & 1u)) >> 16;  // RNE
  return (unsigned short)r;
}
static __device__ __forceinline__ float b2f(unsigned short h) {
  return __uint_as_float(((unsigned int)h) << 16);
}

// ---------------------------------------------------------------------------
// fp32 tiled GEMM: C = A(MxK) @ B(KxN), row-major. Optional bf16 output.
// ---------------------------------------------------------------------------
__global__ __launch_bounds__(256) void sgemm_kernel(
    const float* __restrict__ A, const float* __restrict__ B,
    void* __restrict__ Cv, int M, int N, int K, int bf16_out) {
  __shared__ float As[8][132];  // transposed: As[k][m]
  __shared__ float Bs[8][132];
  const int t = threadIdx.x;
  const int row0 = blockIdx.y * 128;
  const int col0 = blockIdx.x * 128;
  const int a_row = t >> 1, a_col = (t & 1) * 4;
  const int b_row = t >> 5, b_col = (t & 31) * 4;
  const int ty = t >> 4, tx = t & 15;

  float acc[8][8];
#pragma unroll
  for (int i = 0; i < 8; i++)
#pragma unroll
    for (int j = 0; j < 8; j++) acc[i][j] = 0.f;

  const float* Aptr = A + (size_t)(row0 + a_row) * K + a_col;
  const float* Bptr = B + (size_t)b_row * N + col0 + b_col;

  for (int kk = 0; kk < K; kk += 8) {
    float4 av = *(const float4*)(Aptr + kk);
    float4 bv = *(const float4*)(Bptr + (size_t)kk * N);
    __syncthreads();
    As[a_col + 0][a_row] = av.x;
    As[a_col + 1][a_row] = av.y;
    As[a_col + 2][a_row] = av.z;
    As[a_col + 3][a_row] = av.w;
    *(float4*)&Bs[b_row][b_col] = bv;
    __syncthreads();
#pragma unroll
    for (int k = 0; k < 8; k++) {
      float4 a0 = *(float4*)&As[k][ty * 4];
      float4 a1 = *(float4*)&As[k][64 + ty * 4];
      float4 b0 = *(float4*)&Bs[k][tx * 4];
      float4 b1 = *(float4*)&Bs[k][64 + tx * 4];
      float ar[8] = {a0.x, a0.y, a0.z, a0.w, a1.x, a1.y, a1.z, a1.w};
      float br[8] = {b0.x, b0.y, b0.z, b0.w, b1.x, b1.y, b1.z, b1.w};
#pragma unroll
      for (int i = 0; i < 8; i++)
#pragma unroll
        for (int j = 0; j < 8; j++) acc[i][j] = fmaf(ar[i], br[j], acc[i][j]);
    }
  }

#pragma unroll
  for (int i = 0; i < 8; i++) {
    int r = row0 + ((i < 4) ? (ty * 4 + i) : (64 + ty * 4 + (i - 4)));
    if (bf16_out) {
      unsigned short* C16 = (unsigned short*)Cv;
      ushort4 c0 = make_ushort4(f2b(acc[i][0]), f2b(acc[i][1]), f2b(acc[i][2]),
                                f2b(acc[i][3]));
      ushort4 c1 = make_ushort4(f2b(acc[i][4]), f2b(acc[i][5]), f2b(acc[i][6]),
                                f2b(acc[i][7]));
      *(ushort4*)&C16[(size_t)r * N + col0 + tx * 4] = c0;
      *(ushort4*)&C16[(size_t)r * N + col0 + 64 + tx * 4] = c1;
    } else {
      float* C = (float*)Cv;
      float4 c0 = make_float4(acc[i][0], acc[i][1], acc[i][2], acc[i][3]);
      float4 c1 = make_float4(acc[i][4], acc[i][5], acc[i][6], acc[i][7]);
      *(float4*)&C[(size_t)r * N + col0 + tx * 4] = c0;
      *(float4*)&C[(size_t)r * N + col0 + 64 + tx * 4] = c1;
    }
  }
}

// ---------------------------------------------------------------------------
// RoPE in place on bf16 Q (S x 2048) and K (S x 512); Q also scaled 1/sqrt(HD).
// ---------------------------------------------------------------------------
__global__ __launch_bounds__(256) void rope_kernel(unsigned short* __restrict__ Q,
                                                   unsigned short* __restrict__ Kb) {
  int id = blockIdx.x * 256 + threadIdx.x;  // S_LEN * 20 * 64 total
  int d = id & 63;
  int rem = id >> 6;
  int head = rem % 20;
  int s = rem / 20;
  unsigned short* p;
  float scale;
  if (head < N_HEADS) {
    p = Q + (size_t)s * D_MODEL + head * HEAD_DIM;
    scale = 0.08838834764831845f;  // 1/sqrt(128)
  } else {
    p = Kb + (size_t)s * KV_D + (head - N_HEADS) * HEAD_DIM;
    scale = 1.0f;
  }
  float inv = exp2f(-(float)d * (13.287712379549449f / 64.0f));
  float ang = (float)s * inv;
  float sn, c;
  sincosf(ang, &sn, &c);
  float xr = b2f(p[d]), xi = b2f(p[d + 64]);
  p[d] = f2b((xr * c - xi * sn) * scale);
  p[d + 64] = f2b((xr * sn + xi * c) * scale);
}

// ---------------------------------------------------------------------------
// Transpose bf16 V (S x 512) -> Vt (512 x S). 32x32 tiles via LDS.
// ---------------------------------------------------------------------------
__global__ __launch_bounds__(256) void vtrans_kernel(
    const unsigned short* __restrict__ Vb, unsigned short* __restrict__ Vt) {
  __shared__ unsigned short tile[32][33];
  const int t = threadIdx.x;
  const int c0 = blockIdx.x * 32;  // channel
  const int s0 = blockIdx.y * 32;  // sequence
  const int col = t & 31, rbase = t >> 5;
#pragma unroll
  for (int i = 0; i < 4; i++) {
    int row = rbase + i * 8;
    tile[row][col] = Vb[(size_t)(s0 + row) * KV_D + c0 + col];
  }
  __syncthreads();
#pragma unroll
  for (int i = 0; i < 4; i++) {
    int row = rbase + i * 8;
    Vt[(size_t)(c0 + row) * S_LEN + s0 + col] = tile[col][row];
  }
}

// ---------------------------------------------------------------------------
// Flash attention, bf16 MFMA (16x16x32). Block = 256 thr = 4 waves.
// BQ=128 (32 q-rows/wave as 2 M-tiles), BK=64. Q frags in registers.
// K row-major LDS, V pre-transposed LDS, P via per-wave LDS round-trip.
// MFMA layouts (guide-verified): A/B operand [m|n=lane&15][k=quad*8+j],
// C/D [row=quad*4+reg][col=lane&15].
// ---------------------------------------------------------------------------
__global__ __launch_bounds__(256, 2) void attn_kernel(
    const unsigned short* __restrict__ Qb, const unsigned short* __restrict__ Kb,
    const unsigned short* __restrict__ Vt, float* __restrict__ O) {
  __shared__ unsigned short Ks[64][136];      // [k_row][d], pitch 272B (16B-aligned)
  __shared__ unsigned short Vs[128][72];      // [d][k_row], pitch 144B
  __shared__ unsigned short Ps[4][32][72];    // per-wave P, [q_local][k_local]

  const int t = threadIdx.x;
  const int wave = t >> 6;
  const int lane = t & 63;
  const int quad = lane >> 4;
  const int lx = lane & 15;
  const int qt = blockIdx.x;   // 0..31 (128 rows each)
  const int h = blockIdx.y;    // 0..15
  const int kvh = h >> 2;

  // Q fragments: qf[qs][kstep], row = qt*128 + wave*32 + qs*16 + lx
  const unsigned short* Qg =
      Qb + (size_t)(qt * 128 + wave * 32) * D_MODEL + h * HEAD_DIM;
  bf16x8 qf[2][4];
#pragma unroll
  for (int qs = 0; qs < 2; qs++)
#pragma unroll
    for (int ks = 0; ks < 4; ks++)
      qf[qs][ks] = *(const bf16x8*)(Qg + (size_t)(qs * 16 + lx) * D_MODEL +
                                    (quad << 3) + (ks << 5));

  f32x4 oacc[2][8];
#pragma unroll
  for (int qs = 0; qs < 2; qs++)
#pragma unroll
    for (int dt = 0; dt < 8; dt++) oacc[qs][dt] = (f32x4){0.f, 0.f, 0.f, 0.f};
  float m_st[2][4], l_st[2][4];
#pragma unroll
  for (int qs = 0; qs < 2; qs++)
#pragma unroll
    for (int r = 0; r < 4; r++) { m_st[qs][r] = -1e30f; l_st[qs][r] = 0.f; }

  for (int kt = 0; kt < S_LEN / 64; kt++) {
    __syncthreads();  // previous iteration's LDS reads done
    // stage K tile (64x128) and Vt tile (128x64)
    const unsigned short* Kg = Kb + (size_t)(kt * 64) * KV_D + kvh * HEAD_DIM;
    const unsigned short* Vg = Vt + (size_t)(kvh * HEAD_DIM) * S_LEN + kt * 64;
#pragma unroll
    for (int i = 0; i < 4; i++) {
      int c = t + 256 * i;
      int kr = c >> 4, c8 = (c & 15) << 3;
      *(uint4*)&Ks[kr][c8] = *(const uint4*)(Kg + (size_t)kr * KV_D + c8);
    }
#pragma unroll
    for (int i = 0; i < 4; i++) {
      int c = t + 256 * i;
      int d = c >> 3, c8 = (c & 7) << 3;
      *(uint4*)&Vs[d][c8] = *(const uint4*)(Vg + (size_t)d * S_LEN + c8);
    }
    __syncthreads();

    // ---- S = Q @ K^T : sv[qs][ksub] rows q=quad*4+r, col k=ksub*16+lx ----
    f32x4 sv[2][4];
#pragma unroll
    for (int ksub = 0; ksub < 4; ksub++) {
      f32x4 s0 = (f32x4){0.f, 0.f, 0.f, 0.f};
      f32x4 s1 = (f32x4){0.f, 0.f, 0.f, 0.f};
#pragma unroll
      for (int ks = 0; ks < 4; ks++) {
        bf16x8 kf = *(const bf16x8*)&Ks[(ksub << 4) + lx][(quad << 3) + (ks << 5)];
        s0 = __builtin_amdgcn_mfma_f32_16x16x32_bf16(qf[0][ks], kf, s0, 0, 0, 0);
        s1 = __builtin_amdgcn_mfma_f32_16x16x32_bf16(qf[1][ks], kf, s1, 0, 0, 0);
      }
      sv[0][ksub] = s0;
      sv[1][ksub] = s1;
    }

    // ---- online softmax ----
    float alpha[2][4];
#pragma unroll
    for (int qs = 0; qs < 2; qs++)
#pragma unroll
      for (int r = 0; r < 4; r++) {
        float tm = fmaxf(fmaxf(sv[qs][0][r], sv[qs][1][r]),
                         fmaxf(sv[qs][2][r], sv[qs][3][r]));
        tm = fmaxf(tm, __shfl_xor(tm, 1));
        tm = fmaxf(tm, __shfl_xor(tm, 2));
        tm = fmaxf(tm, __shfl_xor(tm, 4));
        tm = fmaxf(tm, __shfl_xor(tm, 8));
        float mn = fmaxf(m_st[qs][r], tm);
        alpha[qs][r] = __expf(m_st[qs][r] - mn);
        m_st[qs][r] = mn;
      }
    float lsum[2][4] = {{0.f, 0.f, 0.f, 0.f}, {0.f, 0.f, 0.f, 0.f}};
#pragma unroll
    for (int qs = 0; qs < 2; qs++)
#pragma unroll
      for (int ksub = 0; ksub < 4; ksub++)
#pragma unroll
        for (int r = 0; r < 4; r++) {
          float p = __expf(sv[qs][ksub][r] - m_st[qs][r]);
          lsum[qs][r] += p;
          Ps[wave][qs * 16 + quad * 4 + r][ksub * 16 + lx] = f2b(p);
        }
#pragma unroll
    for (int qs = 0; qs < 2; qs++)
#pragma unroll
      for (int r = 0; r < 4; r++) {
        float ls = lsum[qs][r];
        ls += __shfl_xor(ls, 1);
        ls += __shfl_xor(ls, 2);
        ls += __shfl_xor(ls, 4);
        ls += __shfl_xor(ls, 8);
        l_st[qs][r] = l_st[qs][r] * alpha[qs][r] + ls;
#pragma unroll
        for (int dt = 0; dt < 8; dt++) oacc[qs][dt][r] *= alpha[qs][r];
      }

    // ---- O += P @ V (P from wave-local LDS; no barrier needed) ----
#pragma unroll
    for (int step = 0; step < 2; step++) {
      bf16x8 a0 = *(const bf16x8*)&Ps[wave][lx][(quad << 3) + (step << 5)];
      bf16x8 a1 = *(const bf16x8*)&Ps[wave][16 + lx][(quad << 3) + (step << 5)];
#pragma unroll
      for (int dt = 0; dt < 8; dt++) {
        bf16x8 vf = *(const bf16x8*)&Vs[lx + (dt << 4)][(quad << 3) + (step << 5)];
        oacc[0][dt] =
            __builtin_amdgcn_mfma_f32_16x16x32_bf16(a0, vf, oacc[0][dt], 0, 0, 0);
        oacc[1][dt] =
            __builtin_amdgcn_mfma_f32_16x16x32_bf16(a1, vf, oacc[1][dt], 0, 0, 0);
      }
    }
  }

  // ---- epilogue: O /= l, store fp32 ----
#pragma unroll
  for (int qs = 0; qs < 2; qs++) {
    float linv[4];
#pragma unroll
    for (int r = 0; r < 4; r++) linv[r] = 1.0f / l_st[qs][r];
#pragma unroll
    for (int dt = 0; dt < 8; dt++)
#pragma unroll
      for (int r = 0; r < 4; r++) {
        int row = qt * 128 + wave * 32 + qs * 16 + quad * 4 + r;
        O[(size_t)row * D_MODEL + h * HEAD_DIM + lx + dt * 16] =
            oacc[qs][dt][r] * linv[r];
      }
  }
}

// ---------------------------------------------------------------------------
extern "C" void kernel_launch(void* const* d_in, const int* in_sizes, int n_in,
                              void* d_out, int out_size, void* d_ws,
                              size_t ws_size, hipStream_t stream) {
  const float* X = (const float*)d_in[0];   // 4096 x 2048
  const float* Wq = (const float*)d_in[1];  // 2048 x 2048
  const float* Wk = (const float*)d_in[2];  // 2048 x 512
  const float* Wv = (const float*)d_in[3];  // 2048 x 512
  const float* Wo = (const float*)d_in[4];  // 2048 x 2048
  float* out = (float*)d_out;               // 4096 x 2048

  char* ws = (char*)d_ws;
  unsigned short* Qbf = (unsigned short*)ws;                   // 16 MiB
  unsigned short* Kbf = (unsigned short*)(ws + 16777216);      //  4 MiB
  unsigned short* Vbf = (unsigned short*)(ws + 20971520);      //  4 MiB
  unsigned short* Vtr = (unsigned short*)(ws + 25165824);      //  4 MiB
  float* Ow = (float*)(ws + 29360128);                         // 32 MiB

  dim3 blk(256);
  // QKV projections (bf16 outputs)
  sgemm_kernel<<<dim3(D_MODEL / 128, S_LEN / 128), blk, 0, stream>>>(
      X, Wq, Qbf, S_LEN, D_MODEL, D_MODEL, 1);
  sgemm_kernel<<<dim3(KV_D / 128, S_LEN / 128), blk, 0, stream>>>(
      X, Wk, Kbf, S_LEN, KV_D, D_MODEL, 1);
  sgemm_kernel<<<dim3(KV_D / 128, S_LEN / 128), blk, 0, stream>>>(
      X, Wv, Vbf, S_LEN, KV_D, D_MODEL, 1);
  // RoPE (in-place bf16, Q scaled by 1/sqrt(HD))
  rope_kernel<<<(S_LEN * 20 * 64) / 256, blk, 0, stream>>>(Qbf, Kbf);
  // V transpose -> Vt (512 x 4096)
  vtrans_kernel<<<dim3(KV_D / 32, S_LEN / 32), blk, 0, stream>>>(Vbf, Vtr);
  // attention (bf16 MFMA), fp32 O
  attn_kernel<<<dim3(S_LEN / 128, N_HEADS), blk, 0, stream>>>(Qbf, Kbf, Vtr, Ow);
  // output projection (fp32)
  sgemm_kernel<<<dim3(D_MODEL / 128, S_LEN / 128), blk, 0, stream>>>(
      Ow, Wo, out, S_LEN, D_MODEL, D_MODEL, 0);
}

// Round 3
// 555.272 us; speedup vs baseline: 9.7635x; 3.2970x over previous
//
#include <hip/hip_runtime.h>
#include <math.h>

#define S_LEN 4096
#define D_MODEL 2048
#define N_HEADS 16
#define N_KV 4
#define HEAD_DIM 128
#define KV_D 512

typedef short bf16x8 __attribute__((ext_vector_type(8)));
typedef float f32x4 __attribute__((ext_vector_type(4)));

static __device__ __forceinline__ unsigned short f2b(float f) {
  unsigned int u = __float_as_uint(f);
  unsigned int r = (u + 0x7FFFu + ((u >> 16) & 1u)) >> 16;  // RNE
  return (unsigned short)r;
}
static __device__ __forceinline__ float b2f(unsigned short h) {
  return __uint_as_float(((unsigned int)h) << 16);
}

// async 16B global -> LDS (wave-uniform base + lane*16 ordering)
static __device__ __forceinline__ void gload_lds16(const unsigned short* g,
                                                   unsigned short* l) {
  __builtin_amdgcn_global_load_lds(
      (const __attribute__((address_space(1))) void*)g,
      (__attribute__((address_space(3))) void*)l, 16, 0, 0);
}

// ---------------------------------------------------------------------------
// X fp32 -> bf16, 8 elements/thread
// ---------------------------------------------------------------------------
__global__ __launch_bounds__(256) void convx_kernel(const float* __restrict__ X,
                                                    unsigned short* __restrict__ Xb) {
  int i = (blockIdx.x * 256 + threadIdx.x) * 8;
  float4 a = *(const float4*)(X + i);
  float4 b = *(const float4*)(X + i + 4);
  unsigned short tmp[8] = {f2b(a.x), f2b(a.y), f2b(a.z), f2b(a.w),
                           f2b(b.x), f2b(b.y), f2b(b.z), f2b(b.w)};
  *(uint4*)&Xb[i] = *(uint4*)tmp;
}

// ---------------------------------------------------------------------------
// W fp32 (K x N) -> W^T bf16 (N x K), 32x32 LDS tile transpose
// ---------------------------------------------------------------------------
__global__ __launch_bounds__(256) void wtrans_kernel(const float* __restrict__ W,
                                                     unsigned short* __restrict__ Wt,
                                                     int K, int N) {
  __shared__ float tile[32][33];
  const int t = threadIdx.x;
  const int c0 = blockIdx.x * 32;  // N dim
  const int r0 = blockIdx.y * 32;  // K dim
  const int col = t & 31, rb = t >> 5;
#pragma unroll
  for (int i = 0; i < 4; i++)
    tile[rb + i * 8][col] = W[(size_t)(r0 + rb + i * 8) * N + c0 + col];
  __syncthreads();
#pragma unroll
  for (int i = 0; i < 4; i++)
    Wt[(size_t)(c0 + rb + i * 8) * K + r0 + col] = f2b(tile[col][rb + i * 8]);
}

// ---------------------------------------------------------------------------
// bf16 MFMA GEMM (m97 structure): C(MxN) = A(MxK) @ Bt(NxK)^T, both row-major
// bf16. 128x128 tile, BK=32, 256 thr = 4 waves (2x2 of 64x64), 4x4 16x16x32
// fragments per wave, global_load_lds 16B staging, unpadded [m][32] LDS.
// blockIdx.z selects (Bt_a,C_a) vs (Bt_b,C_b) so K/V share one launch.
// ---------------------------------------------------------------------------
__global__ __launch_bounds__(256) void bgemm_kernel(
    const unsigned short* __restrict__ A, const unsigned short* __restrict__ Bt_a,
    const unsigned short* __restrict__ Bt_b, void* __restrict__ C_a,
    void* __restrict__ C_b, int M, int N, int K, int bf16_out) {
  __shared__ unsigned short As[128 * 32];
  __shared__ unsigned short Bs[128 * 32];
  const unsigned short* Bt = blockIdx.z ? Bt_b : Bt_a;
  void* C = blockIdx.z ? C_b : C_a;

  const int t = threadIdx.x;
  const int w = t >> 6, l = t & 63;
  const int quad = l >> 4, lx = l & 15;
  const int row0 = blockIdx.y * 128, col0 = blockIdx.x * 128;
  const int wr = (w >> 1) * 64, wc = (w & 1) * 64;

  f32x4 acc[4][4];
#pragma unroll
  for (int mt = 0; mt < 4; mt++)
#pragma unroll
    for (int nt = 0; nt < 4; nt++) acc[mt][nt] = (f32x4){0.f, 0.f, 0.f, 0.f};

  for (int kt = 0; kt < K; kt += 32) {
    __syncthreads();  // previous iteration's fragment reads complete
#pragma unroll
    for (int j = 0; j < 2; j++) {
      int ch = w * 128 + j * 64 + l;      // 16B chunk id, 0..511
      int r = ch >> 2, kc = (ch & 3) * 8; // row, k-offset (elements)
      gload_lds16(A + (size_t)(row0 + r) * K + kt + kc, &As[ch * 8]);
      gload_lds16(Bt + (size_t)(col0 + r) * K + kt + kc, &Bs[ch * 8]);
    }
    __syncthreads();  // drains vmcnt (global_load_lds) then barrier

    bf16x8 af[4], bfr[4];
#pragma unroll
    for (int mt = 0; mt < 4; mt++)
      af[mt] = *(const bf16x8*)&As[(wr + mt * 16 + lx) * 32 + quad * 8];
#pragma unroll
    for (int nt = 0; nt < 4; nt++)
      bfr[nt] = *(const bf16x8*)&Bs[(wc + nt * 16 + lx) * 32 + quad * 8];
#pragma unroll
    for (int mt = 0; mt < 4; mt++)
#pragma unroll
      for (int nt = 0; nt < 4; nt++)
        acc[mt][nt] = __builtin_amdgcn_mfma_f32_16x16x32_bf16(af[mt], bfr[nt],
                                                              acc[mt][nt], 0, 0, 0);
  }

  // epilogue: C[row=quad*4+r][col=lx] per 16x16 tile
  if (bf16_out) {
    unsigned short* Cp = (unsigned short*)C;
#pragma unroll
    for (int mt = 0; mt < 4; mt++)
#pragma unroll
      for (int nt = 0; nt < 4; nt++)
#pragma unroll
        for (int r = 0; r < 4; r++) {
          int row = row0 + wr + mt * 16 + quad * 4 + r;
          int col = col0 + wc + nt * 16 + lx;
          Cp[(size_t)row * N + col] = f2b(acc[mt][nt][r]);
        }
  } else {
    float* Cp = (float*)C;
#pragma unroll
    for (int mt = 0; mt < 4; mt++)
#pragma unroll
      for (int nt = 0; nt < 4; nt++)
#pragma unroll
        for (int r = 0; r < 4; r++) {
          int row = row0 + wr + mt * 16 + quad * 4 + r;
          int col = col0 + wc + nt * 16 + lx;
          Cp[(size_t)row * N + col] = acc[mt][nt][r];
        }
  }
}

// ---------------------------------------------------------------------------
// RoPE in place on bf16 Q (S x 2048) and K (S x 512); Q also scaled 1/sqrt(HD).
// ---------------------------------------------------------------------------
__global__ __launch_bounds__(256) void rope_kernel(unsigned short* __restrict__ Q,
                                                   unsigned short* __restrict__ Kb) {
  int id = blockIdx.x * 256 + threadIdx.x;
  int d = id & 63;
  int rem = id >> 6;
  int head = rem % 20;
  int s = rem / 20;
  unsigned short* p;
  float scale;
  if (head < N_HEADS) {
    p = Q + (size_t)s * D_MODEL + head * HEAD_DIM;
    scale = 0.08838834764831845f;  // 1/sqrt(128)
  } else {
    p = Kb + (size_t)s * KV_D + (head - N_HEADS) * HEAD_DIM;
    scale = 1.0f;
  }
  float inv = exp2f(-(float)d * (13.287712379549449f / 64.0f));
  float ang = (float)s * inv;
  float sn, c;
  sincosf(ang, &sn, &c);
  float xr = b2f(p[d]), xi = b2f(p[d + 64]);
  p[d] = f2b((xr * c - xi * sn) * scale);
  p[d + 64] = f2b((xr * sn + xi * c) * scale);
}

// ---------------------------------------------------------------------------
// Transpose bf16 V (S x 512) -> Vt (512 x S). 32x32 tiles via LDS.
// ---------------------------------------------------------------------------
__global__ __launch_bounds__(256) void vtrans_kernel(
    const unsigned short* __restrict__ Vb, unsigned short* __restrict__ Vt) {
  __shared__ unsigned short tile[32][33];
  const int t = threadIdx.x;
  const int c0 = blockIdx.x * 32;
  const int s0 = blockIdx.y * 32;
  const int col = t & 31, rbase = t >> 5;
#pragma unroll
  for (int i = 0; i < 4; i++) {
    int row = rbase + i * 8;
    tile[row][col] = Vb[(size_t)(s0 + row) * KV_D + c0 + col];
  }
  __syncthreads();
#pragma unroll
  for (int i = 0; i < 4; i++) {
    int row = rbase + i * 8;
    Vt[(size_t)(c0 + row) * S_LEN + s0 + col] = tile[col][row];
  }
}

// ---------------------------------------------------------------------------
// Flash attention, bf16 MFMA (16x16x32). Block = 256 thr = 4 waves.
// BQ=128 (32 q-rows/wave), BK=64. Output bf16 (feeds out-projection GEMM).
// ---------------------------------------------------------------------------
__global__ __launch_bounds__(256, 2) void attn_kernel(
    const unsigned short* __restrict__ Qb, const unsigned short* __restrict__ Kb,
    const unsigned short* __restrict__ Vt, unsigned short* __restrict__ Ob) {
  __shared__ unsigned short Ks[64][136];
  __shared__ unsigned short Vs[128][72];
  __shared__ unsigned short Ps[4][32][72];

  const int t = threadIdx.x;
  const int wave = t >> 6;
  const int lane = t & 63;
  const int quad = lane >> 4;
  const int lx = lane & 15;
  const int qt = blockIdx.x;
  const int h = blockIdx.y;
  const int kvh = h >> 2;

  const unsigned short* Qg =
      Qb + (size_t)(qt * 128 + wave * 32) * D_MODEL + h * HEAD_DIM;
  bf16x8 qf[2][4];
#pragma unroll
  for (int qs = 0; qs < 2; qs++)
#pragma unroll
    for (int ks = 0; ks < 4; ks++)
      qf[qs][ks] = *(const bf16x8*)(Qg + (size_t)(qs * 16 + lx) * D_MODEL +
                                    (quad << 3) + (ks << 5));

  f32x4 oacc[2][8];
#pragma unroll
  for (int qs = 0; qs < 2; qs++)
#pragma unroll
    for (int dt = 0; dt < 8; dt++) oacc[qs][dt] = (f32x4){0.f, 0.f, 0.f, 0.f};
  float m_st[2][4], l_st[2][4];
#pragma unroll
  for (int qs = 0; qs < 2; qs++)
#pragma unroll
    for (int r = 0; r < 4; r++) { m_st[qs][r] = -1e30f; l_st[qs][r] = 0.f; }

  for (int kt = 0; kt < S_LEN / 64; kt++) {
    __syncthreads();
    const unsigned short* Kg = Kb + (size_t)(kt * 64) * KV_D + kvh * HEAD_DIM;
    const unsigned short* Vg = Vt + (size_t)(kvh * HEAD_DIM) * S_LEN + kt * 64;
#pragma unroll
    for (int i = 0; i < 4; i++) {
      int c = t + 256 * i;
      int kr = c >> 4, c8 = (c & 15) << 3;
      *(uint4*)&Ks[kr][c8] = *(const uint4*)(Kg + (size_t)kr * KV_D + c8);
    }
#pragma unroll
    for (int i = 0; i < 4; i++) {
      int c = t + 256 * i;
      int d = c >> 3, c8 = (c & 7) << 3;
      *(uint4*)&Vs[d][c8] = *(const uint4*)(Vg + (size_t)d * S_LEN + c8);
    }
    __syncthreads();

    f32x4 sv[2][4];
#pragma unroll
    for (int ksub = 0; ksub < 4; ksub++) {
      f32x4 s0 = (f32x4){0.f, 0.f, 0.f, 0.f};
      f32x4 s1 = (f32x4){0.f, 0.f, 0.f, 0.f};
#pragma unroll
      for (int ks = 0; ks < 4; ks++) {
        bf16x8 kf = *(const bf16x8*)&Ks[(ksub << 4) + lx][(quad << 3) + (ks << 5)];
        s0 = __builtin_amdgcn_mfma_f32_16x16x32_bf16(qf[0][ks], kf, s0, 0, 0, 0);
        s1 = __builtin_amdgcn_mfma_f32_16x16x32_bf16(qf[1][ks], kf, s1, 0, 0, 0);
      }
      sv[0][ksub] = s0;
      sv[1][ksub] = s1;
    }

    float alpha[2][4];
#pragma unroll
    for (int qs = 0; qs < 2; qs++)
#pragma unroll
      for (int r = 0; r < 4; r++) {
        float tm = fmaxf(fmaxf(sv[qs][0][r], sv[qs][1][r]),
                         fmaxf(sv[qs][2][r], sv[qs][3][r]));
        tm = fmaxf(tm, __shfl_xor(tm, 1));
        tm = fmaxf(tm, __shfl_xor(tm, 2));
        tm = fmaxf(tm, __shfl_xor(tm, 4));
        tm = fmaxf(tm, __shfl_xor(tm, 8));
        float mn = fmaxf(m_st[qs][r], tm);
        alpha[qs][r] = __expf(m_st[qs][r] - mn);
        m_st[qs][r] = mn;
      }
    float lsum[2][4] = {{0.f, 0.f, 0.f, 0.f}, {0.f, 0.f, 0.f, 0.f}};
#pragma unroll
    for (int qs = 0; qs < 2; qs++)
#pragma unroll
      for (int ksub = 0; ksub < 4; ksub++)
#pragma unroll
        for (int r = 0; r < 4; r++) {
          float p = __expf(sv[qs][ksub][r] - m_st[qs][r]);
          lsum[qs][r] += p;
          Ps[wave][qs * 16 + quad * 4 + r][ksub * 16 + lx] = f2b(p);
        }
#pragma unroll
    for (int qs = 0; qs < 2; qs++)
#pragma unroll
      for (int r = 0; r < 4; r++) {
        float ls = lsum[qs][r];
        ls += __shfl_xor(ls, 1);
        ls += __shfl_xor(ls, 2);
        ls += __shfl_xor(ls, 4);
        ls += __shfl_xor(ls, 8);
        l_st[qs][r] = l_st[qs][r] * alpha[qs][r] + ls;
#pragma unroll
        for (int dt = 0; dt < 8; dt++) oacc[qs][dt][r] *= alpha[qs][r];
      }

#pragma unroll
    for (int step = 0; step < 2; step++) {
      bf16x8 a0 = *(const bf16x8*)&Ps[wave][lx][(quad << 3) + (step << 5)];
      bf16x8 a1 = *(const bf16x8*)&Ps[wave][16 + lx][(quad << 3) + (step << 5)];
#pragma unroll
      for (int dt = 0; dt < 8; dt++) {
        bf16x8 vf = *(const bf16x8*)&Vs[lx + (dt << 4)][(quad << 3) + (step << 5)];
        oacc[0][dt] =
            __builtin_amdgcn_mfma_f32_16x16x32_bf16(a0, vf, oacc[0][dt], 0, 0, 0);
        oacc[1][dt] =
            __builtin_amdgcn_mfma_f32_16x16x32_bf16(a1, vf, oacc[1][dt], 0, 0, 0);
      }
    }
  }

#pragma unroll
  for (int qs = 0; qs < 2; qs++) {
    float linv[4];
#pragma unroll
    for (int r = 0; r < 4; r++) linv[r] = 1.0f / l_st[qs][r];
#pragma unroll
    for (int dt = 0; dt < 8; dt++)
#pragma unroll
      for (int r = 0; r < 4; r++) {
        int row = qt * 128 + wave * 32 + qs * 16 + quad * 4 + r;
        Ob[(size_t)row * D_MODEL + h * HEAD_DIM + lx + dt * 16] =
            f2b(oacc[qs][dt][r] * linv[r]);
      }
  }
}

// ---------------------------------------------------------------------------
extern "C" void kernel_launch(void* const* d_in, const int* in_sizes, int n_in,
                              void* d_out, int out_size, void* d_ws,
                              size_t ws_size, hipStream_t stream) {
  const float* X = (const float*)d_in[0];   // 4096 x 2048
  const float* Wq = (const float*)d_in[1];  // 2048 x 2048
  const float* Wk = (const float*)d_in[2];  // 2048 x 512
  const float* Wv = (const float*)d_in[3];  // 2048 x 512
  const float* Wo = (const float*)d_in[4];  // 2048 x 2048
  float* out = (float*)d_out;               // 4096 x 2048

  const size_t MB = 1048576;
  char* ws = (char*)d_ws;
  unsigned short* Xb = (unsigned short*)ws;              // 16 MB
  unsigned short* WqT = (unsigned short*)(ws + 16 * MB); //  8 MB (2048x2048)
  unsigned short* WkT = (unsigned short*)(ws + 24 * MB); //  2 MB (512x2048)
  unsigned short* WvT = (unsigned short*)(ws + 26 * MB); //  2 MB
  unsigned short* WoT = (unsigned short*)(ws + 28 * MB); //  8 MB
  unsigned short* Qbf = (unsigned short*)(ws + 36 * MB); // 16 MB
  unsigned short* Kbf = (unsigned short*)(ws + 52 * MB); //  4 MB
  unsigned short* Vbf = (unsigned short*)(ws + 56 * MB); //  4 MB
  unsigned short* Vtr = (unsigned short*)(ws + 60 * MB); //  4 MB
  unsigned short* Ob  = (unsigned short*)(ws + 64 * MB); // 16 MB -> 80 MB total

  dim3 blk(256);
  // input conversions
  convx_kernel<<<(S_LEN * D_MODEL) / 2048, blk, 0, stream>>>(X, Xb);
  wtrans_kernel<<<dim3(D_MODEL / 32, D_MODEL / 32), blk, 0, stream>>>(Wq, WqT, D_MODEL, D_MODEL);
  wtrans_kernel<<<dim3(KV_D / 32, D_MODEL / 32), blk, 0, stream>>>(Wk, WkT, D_MODEL, KV_D);
  wtrans_kernel<<<dim3(KV_D / 32, D_MODEL / 32), blk, 0, stream>>>(Wv, WvT, D_MODEL, KV_D);
  wtrans_kernel<<<dim3(D_MODEL / 32, D_MODEL / 32), blk, 0, stream>>>(Wo, WoT, D_MODEL, D_MODEL);

  // Q projection (bf16 out)
  bgemm_kernel<<<dim3(D_MODEL / 128, S_LEN / 128, 1), blk, 0, stream>>>(
      Xb, WqT, WqT, Qbf, Qbf, S_LEN, D_MODEL, D_MODEL, 1);
  // K and V projections fused via blockIdx.z
  bgemm_kernel<<<dim3(KV_D / 128, S_LEN / 128, 2), blk, 0, stream>>>(
      Xb, WkT, WvT, Kbf, Vbf, S_LEN, KV_D, D_MODEL, 1);
  // RoPE (in-place bf16, Q scaled by 1/sqrt(HD))
  rope_kernel<<<(S_LEN * 20 * 64) / 256, blk, 0, stream>>>(Qbf, Kbf);
  // V transpose -> Vt (512 x 4096)
  vtrans_kernel<<<dim3(KV_D / 32, S_LEN / 32), blk, 0, stream>>>(Vbf, Vtr);
  // attention (bf16 MFMA), bf16 O
  attn_kernel<<<dim3(S_LEN / 128, N_HEADS), blk, 0, stream>>>(Qbf, Kbf, Vtr, Ob);
  // output projection (fp32 out to d_out)
  bgemm_kernel<<<dim3(D_MODEL / 128, S_LEN / 128, 1), blk, 0, stream>>>(
      Ob, WoT, WoT, out, out, S_LEN, D_MODEL, D_MODEL, 0);
}

// Round 5
// 488.804 us; speedup vs baseline: 11.0911x; 1.1360x over previous
//
#include <hip/hip_runtime.h>
#include <math.h>

#define S_LEN 4096
#define D_MODEL 2048
#define N_HEADS 16
#define N_KV 4
#define HEAD_DIM 128
#define KV_D 512

typedef short bf16x8 __attribute__((ext_vector_type(8)));
typedef float f32x4 __attribute__((ext_vector_type(4)));

static __device__ __forceinline__ unsigned short f2b(float f) {
  unsigned int u = __float_as_uint(f);
  unsigned int r = (u + 0x7FFFu + ((u >> 16) & 1u)) >> 16;  // RNE
  return (unsigned short)r;
}
static __device__ __forceinline__ float b2f(unsigned short h) {
  return __uint_as_float(((unsigned int)h) << 16);
}

// async 16B global -> LDS (wave-uniform base + lane*16 ordering)
static __device__ __forceinline__ void gload_lds16(const unsigned short* g,
                                                   unsigned short* l) {
  __builtin_amdgcn_global_load_lds(
      (const __attribute__((address_space(1))) void*)g,
      (__attribute__((address_space(3))) void*)l, 16, 0, 0);
}

// ---------------------------------------------------------------------------
// X fp32 -> bf16, 8 elements/thread
// ---------------------------------------------------------------------------
__global__ __launch_bounds__(256) void convx_kernel(const float* __restrict__ X,
                                                    unsigned short* __restrict__ Xb) {
  int i = (blockIdx.x * 256 + threadIdx.x) * 8;
  float4 a = *(const float4*)(X + i);
  float4 b = *(const float4*)(X + i + 4);
  unsigned short tmp[8] = {f2b(a.x), f2b(a.y), f2b(a.z), f2b(a.w),
                           f2b(b.x), f2b(b.y), f2b(b.z), f2b(b.w)};
  *(uint4*)&Xb[i] = *(uint4*)tmp;
}

// ---------------------------------------------------------------------------
// W fp32 (K x N) -> W^T bf16 (N x K), 32x32 LDS tile transpose
// ---------------------------------------------------------------------------
__global__ __launch_bounds__(256) void wtrans_kernel(const float* __restrict__ W,
                                                     unsigned short* __restrict__ Wt,
                                                     int K, int N) {
  __shared__ float tile[32][33];
  const int t = threadIdx.x;
  const int c0 = blockIdx.x * 32;  // N dim
  const int r0 = blockIdx.y * 32;  // K dim
  const int col = t & 31, rb = t >> 5;
#pragma unroll
  for (int i = 0; i < 4; i++)
    tile[rb + i * 8][col] = W[(size_t)(r0 + rb + i * 8) * N + c0 + col];
  __syncthreads();
#pragma unroll
  for (int i = 0; i < 4; i++)
    Wt[(size_t)(c0 + rb + i * 8) * K + r0 + col] = f2b(tile[col][rb + i * 8]);
}

// ---------------------------------------------------------------------------
// bf16 MFMA GEMM (m97 structure): C(MxN) = A(MxK) @ Bt(NxK)^T, both row-major
// bf16. 128x128 tile, BK=32, 256 thr = 4 waves, global_load_lds staging.
// ---------------------------------------------------------------------------
__global__ __launch_bounds__(256) void bgemm_kernel(
    const unsigned short* __restrict__ A, const unsigned short* __restrict__ Bt_a,
    const unsigned short* __restrict__ Bt_b, void* __restrict__ C_a,
    void* __restrict__ C_b, int M, int N, int K, int bf16_out) {
  __shared__ unsigned short As[128 * 32];
  __shared__ unsigned short Bs[128 * 32];
  const unsigned short* Bt = blockIdx.z ? Bt_b : Bt_a;
  void* C = blockIdx.z ? C_b : C_a;

  const int t = threadIdx.x;
  const int w = t >> 6, l = t & 63;
  const int quad = l >> 4, lx = l & 15;
  const int row0 = blockIdx.y * 128, col0 = blockIdx.x * 128;
  const int wr = (w >> 1) * 64, wc = (w & 1) * 64;

  f32x4 acc[4][4];
#pragma unroll
  for (int mt = 0; mt < 4; mt++)
#pragma unroll
    for (int nt = 0; nt < 4; nt++) acc[mt][nt] = (f32x4){0.f, 0.f, 0.f, 0.f};

  for (int kt = 0; kt < K; kt += 32) {
    __syncthreads();
#pragma unroll
    for (int j = 0; j < 2; j++) {
      int ch = w * 128 + j * 64 + l;
      int r = ch >> 2, kc = (ch & 3) * 8;
      gload_lds16(A + (size_t)(row0 + r) * K + kt + kc, &As[ch * 8]);
      gload_lds16(Bt + (size_t)(col0 + r) * K + kt + kc, &Bs[ch * 8]);
    }
    __syncthreads();

    bf16x8 af[4], bfr[4];
#pragma unroll
    for (int mt = 0; mt < 4; mt++)
      af[mt] = *(const bf16x8*)&As[(wr + mt * 16 + lx) * 32 + quad * 8];
#pragma unroll
    for (int nt = 0; nt < 4; nt++)
      bfr[nt] = *(const bf16x8*)&Bs[(wc + nt * 16 + lx) * 32 + quad * 8];
#pragma unroll
    for (int mt = 0; mt < 4; mt++)
#pragma unroll
      for (int nt = 0; nt < 4; nt++)
        acc[mt][nt] = __builtin_amdgcn_mfma_f32_16x16x32_bf16(af[mt], bfr[nt],
                                                              acc[mt][nt], 0, 0, 0);
  }

  if (bf16_out) {
    unsigned short* Cp = (unsigned short*)C;
#pragma unroll
    for (int mt = 0; mt < 4; mt++)
#pragma unroll
      for (int nt = 0; nt < 4; nt++)
#pragma unroll
        for (int r = 0; r < 4; r++) {
          int row = row0 + wr + mt * 16 + quad * 4 + r;
          int col = col0 + wc + nt * 16 + lx;
          Cp[(size_t)row * N + col] = f2b(acc[mt][nt][r]);
        }
  } else {
    float* Cp = (float*)C;
#pragma unroll
    for (int mt = 0; mt < 4; mt++)
#pragma unroll
      for (int nt = 0; nt < 4; nt++)
#pragma unroll
        for (int r = 0; r < 4; r++) {
          int row = row0 + wr + mt * 16 + quad * 4 + r;
          int col = col0 + wc + nt * 16 + lx;
          Cp[(size_t)row * N + col] = acc[mt][nt][r];
        }
  }
}

// ---------------------------------------------------------------------------
// RoPE in place on bf16 Q (S x 2048) and K (S x 512); Q also scaled 1/sqrt(HD).
// ---------------------------------------------------------------------------
__global__ __launch_bounds__(256) void rope_kernel(unsigned short* __restrict__ Q,
                                                   unsigned short* __restrict__ Kb) {
  int id = blockIdx.x * 256 + threadIdx.x;
  int d = id & 63;
  int rem = id >> 6;
  int head = rem % 20;
  int s = rem / 20;
  unsigned short* p;
  float scale;
  if (head < N_HEADS) {
    p = Q + (size_t)s * D_MODEL + head * HEAD_DIM;
    scale = 0.08838834764831845f;  // 1/sqrt(128)
  } else {
    p = Kb + (size_t)s * KV_D + (head - N_HEADS) * HEAD_DIM;
    scale = 1.0f;
  }
  float inv = exp2f(-(float)d * (13.287712379549449f / 64.0f));
  float ang = (float)s * inv;
  float sn, c;
  sincosf(ang, &sn, &c);
  float xr = b2f(p[d]), xi = b2f(p[d + 64]);
  p[d] = f2b((xr * c - xi * sn) * scale);
  p[d + 64] = f2b((xr * sn + xi * c) * scale);
}

// ---------------------------------------------------------------------------
// Transpose bf16 V (S x 512) -> Vt (512 x S). 32x32 tiles via LDS.
// ---------------------------------------------------------------------------
__global__ __launch_bounds__(256) void vtrans_kernel(
    const unsigned short* __restrict__ Vb, unsigned short* __restrict__ Vt) {
  __shared__ unsigned short tile[32][33];
  const int t = threadIdx.x;
  const int c0 = blockIdx.x * 32;
  const int s0 = blockIdx.y * 32;
  const int col = t & 31, rbase = t >> 5;
#pragma unroll
  for (int i = 0; i < 4; i++) {
    int row = rbase + i * 8;
    tile[row][col] = Vb[(size_t)(s0 + row) * KV_D + c0 + col];
  }
  __syncthreads();
#pragma unroll
  for (int i = 0; i < 4; i++) {
    int row = rbase + i * 8;
    Vt[(size_t)(c0 + row) * S_LEN + s0 + col] = tile[col][row];
  }
}

// ---------------------------------------------------------------------------
// Flash attention, transposed-score form. Block = 256 thr = 4 waves, BQ=128
// (32 q/wave), BK=64. S^T = K@Q^T so softmax is in-lane + 2 shuffles; P^T
// round-trips a per-wave LDS buffer as packed b64 writes / b128 reads.
// O^T = V^T @ P^T. K/V double-buffered via global_load_lds with XOR-swizzled
// source addressing (unpadded tiles, conflict-free b128 fragment reads).
// R5 fix: K staging must cover 1024 chunks (j<4), not 512 — rows 32..63 were
// stale in R4.
// ---------------------------------------------------------------------------
__global__ __launch_bounds__(256, 2) void attn_kernel(
    const unsigned short* __restrict__ Qb, const unsigned short* __restrict__ Kb,
    const unsigned short* __restrict__ Vt, unsigned short* __restrict__ Ob) {
  __shared__ unsigned short Ks[2][64 * 128];   // [krow][d], chunk-swizzled
  __shared__ unsigned short Vs[2][128 * 64];   // [d][krow], chunk-swizzled
  __shared__ unsigned short Pt[4][32 * 64];    // per-wave P^T [q][k], swizzled

  const int t = threadIdx.x;
  const int wave = t >> 6;
  const int lane = t & 63;
  const int quad = lane >> 4;
  const int lx = lane & 15;
  const int lx7 = lx & 7;
  const int qt = blockIdx.x;   // 0..31
  const int h = blockIdx.y;    // 0..15
  const int kvh = h >> 2;

  const unsigned short* Kg = Kb + kvh * HEAD_DIM;
  const unsigned short* Vg = Vt + (size_t)(kvh * HEAD_DIM) * S_LEN;

  // Q fragments (registers for whole kernel): B-operand [n=lx][k=quad*8+j]
  const unsigned short* Qg =
      Qb + (size_t)(qt * 128 + wave * 32) * D_MODEL + h * HEAD_DIM;
  bf16x8 qf[2][4];
#pragma unroll
  for (int qs = 0; qs < 2; qs++)
#pragma unroll
    for (int ks = 0; ks < 4; ks++)
      qf[qs][ks] = *(const bf16x8*)(Qg + (size_t)(qs * 16 + lx) * D_MODEL +
                                    (quad << 3) + (ks << 5));

  f32x4 oacc[2][8];
#pragma unroll
  for (int qs = 0; qs < 2; qs++)
#pragma unroll
    for (int dt = 0; dt < 8; dt++) oacc[qs][dt] = (f32x4){0.f, 0.f, 0.f, 0.f};
  float m_st[2] = {-1e30f, -1e30f}, l_st[2] = {0.f, 0.f};

  // K tile: 64 rows x 16 chunks; slot(r,c) holds global chunk (r, c^(r&7)).
  // V^T tile: 128 rows x 8 chunks; same self-inverse XOR swizzle.
  auto stage = [&](int kt, int b) {
#pragma unroll
    for (int j = 0; j < 4; j++) {  // 4*4 waves*64 lanes = 1024 chunks
      int ch = (j * 4 + wave) * 64 + lane;
      int r = ch >> 4, c = ch & 15;
      gload_lds16(Kg + (size_t)(kt * 64 + r) * KV_D + (((c ^ (r & 7)) << 3)),
                  &Ks[b][ch * 8]);
    }
#pragma unroll
    for (int j = 0; j < 4; j++) {
      int ch = (j * 4 + wave) * 64 + lane;
      int d = ch >> 3, c = ch & 7;
      gload_lds16(Vg + (size_t)d * S_LEN + kt * 64 + ((c ^ (d & 7)) << 3),
                  &Vs[b][ch * 8]);
    }
  };

  stage(0, 0);

  for (int kt = 0; kt < S_LEN / 64; kt++) {
    __syncthreads();  // drains this wave's staging vmcnt; tiles now visible
    if (kt + 1 < S_LEN / 64) stage(kt + 1, (kt + 1) & 1);  // prefetch overlap
    const unsigned short* KsC = Ks[kt & 1];
    const unsigned short* VsC = Vs[kt & 1];

    // ---- S^T = K @ Q^T : sv[ksub][qs], k = ksub*16+quad*4+r, q = qs*16+lx
    f32x4 sv[4][2];
#pragma unroll
    for (int ksub = 0; ksub < 4; ksub++) {
      bf16x8 kf[4];
#pragma unroll
      for (int ks = 0; ks < 4; ks++)
        kf[ks] = *(const bf16x8*)&KsC[(ksub * 16 + lx) * 128 +
                                      (((ks * 4 + quad) ^ lx7) << 3)];
#pragma unroll
      for (int qs = 0; qs < 2; qs++) {
        f32x4 a = (f32x4){0.f, 0.f, 0.f, 0.f};
#pragma unroll
        for (int ks = 0; ks < 4; ks++)
          a = __builtin_amdgcn_mfma_f32_16x16x32_bf16(kf[ks], qf[qs][ks], a, 0, 0, 0);
        sv[ksub][qs] = a;
      }
    }

    // ---- online softmax over k (in-lane 16 values + 2 quad-shuffles) ----
#pragma unroll
    for (int qs = 0; qs < 2; qs++) {
      float tm = sv[0][qs][0];
#pragma unroll
      for (int ksub = 0; ksub < 4; ksub++)
#pragma unroll
        for (int r = 0; r < 4; r++) tm = fmaxf(tm, sv[ksub][qs][r]);
      tm = fmaxf(tm, __shfl_xor(tm, 16));
      tm = fmaxf(tm, __shfl_xor(tm, 32));
      float mn = fmaxf(m_st[qs], tm);
      float al = __expf(m_st[qs] - mn);
      m_st[qs] = mn;
      float ls = 0.f;
#pragma unroll
      for (int ksub = 0; ksub < 4; ksub++) {
        float p0 = __expf(sv[ksub][qs][0] - mn);
        float p1 = __expf(sv[ksub][qs][1] - mn);
        float p2 = __expf(sv[ksub][qs][2] - mn);
        float p3 = __expf(sv[ksub][qs][3] - mn);
        ls += (p0 + p1) + (p2 + p3);
        ushort4 pk = make_ushort4(f2b(p0), f2b(p1), f2b(p2), f2b(p3));
        // P^T[q][k]: k = ksub*16+quad*4 (+r), chunk 2ksub+(quad>>1), sub (quad&1)*4
        *(ushort4*)&Pt[wave][(qs * 16 + lx) * 64 +
                             (((2 * ksub + (quad >> 1)) ^ lx7) << 3) +
                             ((quad & 1) << 2)] = pk;
      }
      ls += __shfl_xor(ls, 16);
      ls += __shfl_xor(ls, 32);
      l_st[qs] = l_st[qs] * al + ls;
#pragma unroll
      for (int dt = 0; dt < 8; dt++) {
        oacc[qs][dt][0] *= al; oacc[qs][dt][1] *= al;
        oacc[qs][dt][2] *= al; oacc[qs][dt][3] *= al;
      }
    }

    // ---- O^T += V^T @ P^T (Pt wave-local: lgkm wait only, no barrier) ----
#pragma unroll
    for (int st = 0; st < 2; st++) {
      const int pc = ((st * 4 + quad) ^ lx7) << 3;
      bf16x8 pb0 = *(const bf16x8*)&Pt[wave][lx * 64 + pc];
      bf16x8 pb1 = *(const bf16x8*)&Pt[wave][(16 + lx) * 64 + pc];
#pragma unroll
      for (int dt = 0; dt < 8; dt++) {
        bf16x8 vf = *(const bf16x8*)&VsC[(dt * 16 + lx) * 64 + pc];
        oacc[0][dt] = __builtin_amdgcn_mfma_f32_16x16x32_bf16(vf, pb0, oacc[0][dt], 0, 0, 0);
        oacc[1][dt] = __builtin_amdgcn_mfma_f32_16x16x32_bf16(vf, pb1, oacc[1][dt], 0, 0, 0);
      }
    }
  }

  // ---- epilogue: O = (O^T)^T / l, packed 8B stores ----
#pragma unroll
  for (int qs = 0; qs < 2; qs++) {
    float linv = 1.0f / l_st[qs];
    unsigned short* ob = Ob +
        (size_t)(qt * 128 + wave * 32 + qs * 16 + lx) * D_MODEL + h * HEAD_DIM +
        quad * 4;
#pragma unroll
    for (int dt = 0; dt < 8; dt++) {
      ushort4 o4 = make_ushort4(
          f2b(oacc[qs][dt][0] * linv), f2b(oacc[qs][dt][1] * linv),
          f2b(oacc[qs][dt][2] * linv), f2b(oacc[qs][dt][3] * linv));
      *(ushort4*)&ob[dt * 16] = o4;
    }
  }
}

// ---------------------------------------------------------------------------
extern "C" void kernel_launch(void* const* d_in, const int* in_sizes, int n_in,
                              void* d_out, int out_size, void* d_ws,
                              size_t ws_size, hipStream_t stream) {
  const float* X = (const float*)d_in[0];   // 4096 x 2048
  const float* Wq = (const float*)d_in[1];  // 2048 x 2048
  const float* Wk = (const float*)d_in[2];  // 2048 x 512
  const float* Wv = (const float*)d_in[3];  // 2048 x 512
  const float* Wo = (const float*)d_in[4];  // 2048 x 2048
  float* out = (float*)d_out;               // 4096 x 2048

  const size_t MB = 1048576;
  char* ws = (char*)d_ws;
  unsigned short* Xb = (unsigned short*)ws;              // 16 MB
  unsigned short* WqT = (unsigned short*)(ws + 16 * MB); //  8 MB
  unsigned short* WkT = (unsigned short*)(ws + 24 * MB); //  2 MB
  unsigned short* WvT = (unsigned short*)(ws + 26 * MB); //  2 MB
  unsigned short* WoT = (unsigned short*)(ws + 28 * MB); //  8 MB
  unsigned short* Qbf = (unsigned short*)(ws + 36 * MB); // 16 MB
  unsigned short* Kbf = (unsigned short*)(ws + 52 * MB); //  4 MB
  unsigned short* Vbf = (unsigned short*)(ws + 56 * MB); //  4 MB
  unsigned short* Vtr = (unsigned short*)(ws + 60 * MB); //  4 MB
  unsigned short* Ob  = (unsigned short*)(ws + 64 * MB); // 16 MB

  dim3 blk(256);
  convx_kernel<<<(S_LEN * D_MODEL) / 2048, blk, 0, stream>>>(X, Xb);
  wtrans_kernel<<<dim3(D_MODEL / 32, D_MODEL / 32), blk, 0, stream>>>(Wq, WqT, D_MODEL, D_MODEL);
  wtrans_kernel<<<dim3(KV_D / 32, D_MODEL / 32), blk, 0, stream>>>(Wk, WkT, D_MODEL, KV_D);
  wtrans_kernel<<<dim3(KV_D / 32, D_MODEL / 32), blk, 0, stream>>>(Wv, WvT, D_MODEL, KV_D);
  wtrans_kernel<<<dim3(D_MODEL / 32, D_MODEL / 32), blk, 0, stream>>>(Wo, WoT, D_MODEL, D_MODEL);

  bgemm_kernel<<<dim3(D_MODEL / 128, S_LEN / 128, 1), blk, 0, stream>>>(
      Xb, WqT, WqT, Qbf, Qbf, S_LEN, D_MODEL, D_MODEL, 1);
  bgemm_kernel<<<dim3(KV_D / 128, S_LEN / 128, 2), blk, 0, stream>>>(
      Xb, WkT, WvT, Kbf, Vbf, S_LEN, KV_D, D_MODEL, 1);
  rope_kernel<<<(S_LEN * 20 * 64) / 256, blk, 0, stream>>>(Qbf, Kbf);
  vtrans_kernel<<<dim3(KV_D / 32, S_LEN / 32), blk, 0, stream>>>(Vbf, Vtr);
  attn_kernel<<<dim3(S_LEN / 128, N_HEADS), blk, 0, stream>>>(Qbf, Kbf, Vtr, Ob);
  bgemm_kernel<<<dim3(D_MODEL / 128, S_LEN / 128, 1), blk, 0, stream>>>(
      Ob, WoT, WoT, out, out, S_LEN, D_MODEL, D_MODEL, 0);
}